// Round 12
// baseline (57.055 us; speedup 1.0000x reference)
//
#include <hip/hip_runtime.h>
#include <math.h>

#define BB 8
#define FF 64
#define NN 256
#define EPSF 1e-9f

typedef float floatx4 __attribute__((ext_vector_type(4)));

// ws layout (floats), all within [0..16384):
// ws[mat*16 + job]          trace partial   (mat 0..511, job 0..9)
// ws[8192 + mat*16 + job]   trace_sq partial
// spare slots job=10..15 reused for stats:
//   ws[b*16 + 10]  meanb[b]   (b 0..7)
//   ws[b*16 + 11]  istd[b]
//   ws[f*16 + 12]  g[f]       (f 0..63)
//   ws[f*16 + 13]  bias[f]

__device__ __forceinline__ int fit(int e) {
    constexpr int IT[10] = {0,1,2,3, 0,0,0,1,1,2};
    return IT[e];
}
__device__ __forceinline__ int fkt(int e) {
    constexpr int KT[10] = {0,1,2,3, 1,2,3,2,3,3};
    return KT[e];
}

// One block per (matrix, tile-job). Single barrier; scheduler pipelines blocks.
__global__ __launch_bounds__(256, 8) void k_traces(const float* __restrict__ x,
                                                   const float* __restrict__ mask,
                                                   float* __restrict__ ws) {
    __shared__ float T1[64][65];
    __shared__ float mdi[64], mdk[64];
    __shared__ float red[4][2];

    const int t   = threadIdx.x;
    const int mat = blockIdx.x;       // 0..511  (= b*64 + f)
    const int job = blockIdx.y;       // 0..9
    const int b   = mat >> 6;
    const int i0  = fit(job) << 6;
    const int k0  = fkt(job) << 6;
    const bool diag = (job < 4);
    const float* __restrict__ xm = x + (size_t)mat * (NN * NN);

    if (t < 64)       { float m = mask[b * NN + i0 + t];      mdi[t]      = m * m; }
    else if (t < 128) { float m = mask[b * NN + k0 + t - 64]; mdk[t - 64] = m * m; }

    const int la  = t >> 4;           // 0..15
    const int lc4 = (t & 15) << 2;    // 0,4,...,60
    const int lane = t & 63;
    const int w    = t >> 6;

    float4 p[4];
    float4 u[4];                      // partner tile x[k0.., i0..] stays in regs
    #pragma unroll
    for (int rr = 0; rr < 4; ++rr) {
        const int a = la + (rr << 4);
        p[rr] = *(const float4*)(xm + (size_t)(i0 + a) * NN + k0 + lc4);
        if (!diag)
            u[rr] = *(const float4*)(xm + (size_t)(k0 + a) * NN + i0 + lc4);
    }
    #pragma unroll
    for (int rr = 0; rr < 4; ++rr) {
        const int a = la + (rr << 4);
        T1[a][lc4 + 0] = p[rr].x; T1[a][lc4 + 1] = p[rr].y;
        T1[a][lc4 + 2] = p[rr].z; T1[a][lc4 + 3] = p[rr].w;
    }
    __syncthreads();

    float acc2 = 0.f, trp = 0.f;
    if (!diag) {
        #pragma unroll
        for (int rr = 0; rr < 4; ++rr) {
            const int c = la + (rr << 4);
            const float mk = mdk[c];
            acc2 += T1[lc4 + 0][c] * u[rr].x * (mdi[lc4 + 0] + mk);
            acc2 += T1[lc4 + 1][c] * u[rr].y * (mdi[lc4 + 1] + mk);
            acc2 += T1[lc4 + 2][c] * u[rr].z * (mdi[lc4 + 2] + mk);
            acc2 += T1[lc4 + 3][c] * u[rr].w * (mdi[lc4 + 3] + mk);
        }
    } else {
        #pragma unroll
        for (int s = 0; s < 16; ++s) {
            const int a = w + (s << 2);
            acc2 += T1[a][lane] * T1[lane][a] * mdi[a];
            if (lane == a) trp += T1[a][a] * mdi[a];
        }
    }

    #pragma unroll
    for (int off = 32; off > 0; off >>= 1) {
        acc2 += __shfl_down(acc2, off);
        trp  += __shfl_down(trp,  off);
    }
    if (lane == 0) { red[w][0] = trp; red[w][1] = acc2; }
    __syncthreads();
    if (t == 0) {
        ws[(mat << 4) + job]        = red[0][0] + red[1][0] + red[2][0] + red[3][0];
        ws[8192 + (mat << 4) + job] = red[0][1] + red[1][1] + red[2][1] + red[3][1];
    }
}

// Tiny stats kernel: wave b reduces batch b (lane = feature). Also emits g/bias.
__global__ __launch_bounds__(512) void k_stats(const float* __restrict__ mask,
                                               const float* __restrict__ wt,
                                               const float* __restrict__ wexp,
                                               const float* __restrict__ wbias,
                                               const float* __restrict__ bias,
                                               float* __restrict__ ws) {
    const int t    = threadIdx.x;
    const int b    = t >> 6;          // 0..7
    const int lane = t & 63;          // = feature
    const int base = ((b << 6) + lane) << 4;
    float trf = 0.f, tsf = 0.f;
    #pragma unroll
    for (int j = 0; j < 10; ++j) {
        trf += ws[base + j];
        tsf += ws[8192 + base + j];
    }
    float tr2 = trf * trf;
    float m0 = mask[(b << 8) + lane];
    float m1 = mask[(b << 8) + lane + 64];
    float m2 = mask[(b << 8) + lane + 128];
    float m3 = mask[(b << 8) + lane + 192];
    float nn = m0 * m0 + m1 * m1 + m2 * m2 + m3 * m3;
    #pragma unroll
    for (int off = 32; off > 0; off >>= 1) {
        trf += __shfl_down(trf, off);
        tr2 += __shfl_down(tr2, off);
        tsf += __shfl_down(tsf, off);
        nn  += __shfl_down(nn,  off);
    }
    if (lane == 0) {
        float n  = nn;
        float n2 = fmaxf(n - 1.f, 1.f);
        ws[(b << 4) + 10] = trf / (64.f * n);
        ws[(b << 4) + 11] = 1.f / sqrtf(tsf / (64.f * n2) - tr2 / (64.f * n * n2) + EPSF);
    }
    if (t < FF) {
        ws[(t << 4) + 12] = wt[t] * expf(wexp[t]) + wbias[t];
        ws[(t << 4) + 13] = bias[t];
    }
}

// One block per (matrix, 64-row slab). Stats are 4 uniform scalar loads.
// Mask-aware: rows with m_i == 0 need no x read (wave-uniform branch).
__global__ __launch_bounds__(256) void k_out(const float* __restrict__ x,
                                             const float* __restrict__ mask,
                                             const float* __restrict__ ws,
                                             float* __restrict__ out) {
    __shared__ float md[NN];

    const int t   = threadIdx.x;
    const int mat = blockIdx.x;   // 0..511
    const int q   = blockIdx.y;   // 0..3  (row slab)
    const int b   = mat >> 6;
    const int f   = mat & 63;

    { float m = mask[(b << 8) + t]; md[t] = m * m; }

    const float meanb = ws[(b << 4) + 10];
    const float istd  = ws[(b << 4) + 11];
    const float gs    = ws[(f << 4) + 12];
    const float bs    = ws[(f << 4) + 13];
    __syncthreads();

    const int lane = t & 63;
    const int w    = t >> 6;
    const float* __restrict__ xm = x + (size_t)mat * (NN * NN);
    float* __restrict__       om = out + (size_t)mat * (NN * NN);

    const int r0 = q << 6;
    const int j0 = lane << 2;               // 0..252: fixed per thread
    const float4 mj = *(const float4*)&md[j0];
    const float mjx = mj.x * istd * gs, mjy = mj.y * istd * gs,
                mjz = mj.z * istd * gs, mjw = mj.w * istd * gs;

    #pragma unroll
    for (int rr = 0; rr < 16; ++rr) {
        const int i = r0 + w + (rr << 2);   // wave-uniform row
        const float mi = md[i];             // LDS broadcast (wave-uniform)
        floatx4 o;
        if (mi != 0.f) {
            const float4 xv = *(const float4*)(xm + (size_t)i * NN + j0);
            o.x = (xv.x - (i == j0     ? meanb : 0.f)) * mjx * mi + (i == j0     ? bs : 0.f);
            o.y = (xv.y - (i == j0 + 1 ? meanb : 0.f)) * mjy * mi + (i == j0 + 1 ? bs : 0.f);
            o.z = (xv.z - (i == j0 + 2 ? meanb : 0.f)) * mjz * mi + (i == j0 + 2 ? bs : 0.f);
            o.w = (xv.w - (i == j0 + 3 ? meanb : 0.f)) * mjw * mi + (i == j0 + 3 ? bs : 0.f);
        } else {
            o.x = (i == j0    ) ? bs : 0.f;
            o.y = (i == j0 + 1) ? bs : 0.f;
            o.z = (i == j0 + 2) ? bs : 0.f;
            o.w = (i == j0 + 3) ? bs : 0.f;
        }
        __builtin_nontemporal_store(o, (floatx4*)(om + (size_t)i * NN + j0));
    }
}

extern "C" void kernel_launch(void* const* d_in, const int* in_sizes, int n_in,
                              void* d_out, int out_size, void* d_ws, size_t ws_size,
                              hipStream_t stream) {
    const float* x     = (const float*)d_in[0];
    const float* mask  = (const float*)d_in[1];
    const float* wt    = (const float*)d_in[2];
    const float* wexp  = (const float*)d_in[3];
    const float* wbias = (const float*)d_in[4];
    const float* bias  = (const float*)d_in[5];
    float* out = (float*)d_out;
    float* ws  = (float*)d_ws;

    hipLaunchKernelGGL(k_traces, dim3(512, 10), dim3(256), 0, stream, x, mask, ws);
    hipLaunchKernelGGL(k_stats,  dim3(1),       dim3(512), 0, stream,
                       mask, wt, wexp, wbias, bias, ws);
    hipLaunchKernelGGL(k_out,    dim3(512, 4),  dim3(256), 0, stream, x, mask, ws, out);
}

// Round 13
// 55.496 us; speedup vs baseline: 1.0281x; 1.0281x over previous
//
#include <hip/hip_runtime.h>
#include <math.h>

#define BB 8
#define FF 64
#define NN 256
#define EPSF 1e-9f

typedef float floatx4 __attribute__((ext_vector_type(4)));

// ws layout (floats):
// [0..8191]     trace partial:    ws[mat*16 + job]          (mat=bf 0..511, job 0..9)
// [8192..16383] trace_sq partial: ws[8192 + mat*16 + job]

// job 0..3: diagonal tiles (d,d); job 4..9: off-diag pairs (p,q), p<q
__device__ __forceinline__ int fit(int e) {
    constexpr int IT[10] = {0,1,2,3, 0,0,0,1,1,2};
    return IT[e];
}
__device__ __forceinline__ int fkt(int e) {
    constexpr int KT[10] = {0,1,2,3, 1,2,3,2,3,3};
    return KT[e];
}

// One block per (matrix, tile-job). Single barrier; scheduler pipelines blocks.
__global__ __launch_bounds__(256, 6) void k_traces(const float* __restrict__ x,
                                                   const float* __restrict__ mask,
                                                   float* __restrict__ ws) {
    __shared__ float T1[64][65];
    __shared__ float mdi[64], mdk[64];
    __shared__ float red[4][2];

    const int t   = threadIdx.x;
    const int mat = blockIdx.x;       // 0..511  (= b*64 + f)
    const int job = blockIdx.y;       // 0..9
    const int b   = mat >> 6;
    const int i0  = fit(job) << 6;
    const int k0  = fkt(job) << 6;
    const bool diag = (job < 4);
    const float* __restrict__ xm = x + (size_t)mat * (NN * NN);

    if (t < 64)       { float m = mask[b * NN + i0 + t];      mdi[t]      = m * m; }
    else if (t < 128) { float m = mask[b * NN + k0 + t - 64]; mdk[t - 64] = m * m; }

    const int la  = t >> 4;           // 0..15
    const int lc4 = (t & 15) << 2;    // 0,4,...,60
    const int lane = t & 63;
    const int w    = t >> 6;

    float4 p[4];
    float4 u[4];                      // partner tile x[k0.., i0..] stays in regs
    #pragma unroll
    for (int rr = 0; rr < 4; ++rr) {
        const int a = la + (rr << 4);
        p[rr] = *(const float4*)(xm + (size_t)(i0 + a) * NN + k0 + lc4);
        if (!diag)
            u[rr] = *(const float4*)(xm + (size_t)(k0 + a) * NN + i0 + lc4);
    }
    #pragma unroll
    for (int rr = 0; rr < 4; ++rr) {
        const int a = la + (rr << 4);
        T1[a][lc4 + 0] = p[rr].x; T1[a][lc4 + 1] = p[rr].y;
        T1[a][lc4 + 2] = p[rr].z; T1[a][lc4 + 3] = p[rr].w;
    }
    __syncthreads();

    float acc2 = 0.f, trp = 0.f;
    if (!diag) {
        #pragma unroll
        for (int rr = 0; rr < 4; ++rr) {
            const int c = la + (rr << 4);
            const float mk = mdk[c];
            acc2 += T1[lc4 + 0][c] * u[rr].x * (mdi[lc4 + 0] + mk);
            acc2 += T1[lc4 + 1][c] * u[rr].y * (mdi[lc4 + 1] + mk);
            acc2 += T1[lc4 + 2][c] * u[rr].z * (mdi[lc4 + 2] + mk);
            acc2 += T1[lc4 + 3][c] * u[rr].w * (mdi[lc4 + 3] + mk);
        }
    } else {
        #pragma unroll
        for (int s = 0; s < 16; ++s) {
            const int a = w + (s << 2);
            acc2 += T1[a][lane] * T1[lane][a] * mdi[a];
            if (lane == a) trp += T1[a][a] * mdi[a];
        }
    }

    #pragma unroll
    for (int off = 32; off > 0; off >>= 1) {
        acc2 += __shfl_down(acc2, off);
        trp  += __shfl_down(trp,  off);
    }
    if (lane == 0) { red[w][0] = trp; red[w][1] = acc2; }
    __syncthreads();
    if (t == 0) {
        ws[(mat << 4) + job]        = red[0][0] + red[1][0] + red[2][0] + red[3][0];
        ws[8192 + (mat << 4) + job] = red[0][1] + red[1][1] + red[2][1] + red[3][1];
    }
}

// One block per (matrix, 64-row slab). Mask-aware: rows with m_i == 0 produce
// bias[f]*delta_ij only -> no x read (wave-uniform branch, ~50% of rows).
__global__ __launch_bounds__(256) void k_out(const float* __restrict__ x,
                                             const float* __restrict__ mask,
                                             const float* __restrict__ wt,
                                             const float* __restrict__ wexp,
                                             const float* __restrict__ wbias,
                                             const float* __restrict__ bias,
                                             const float* __restrict__ ws,
                                             float* __restrict__ out) {
    __shared__ float md[NN];
    __shared__ float sstats[4];   // meanb, istd, g, bias_f

    const int t   = threadIdx.x;
    const int mat = blockIdx.x;   // 0..511
    const int q   = blockIdx.y;   // 0..3  (row slab)
    const int b   = mat >> 6;
    const int f   = mat & 63;

    { float m = mask[(b << 8) + t]; md[t] = m * m; }

    const int lane = t & 63;
    const int w    = t >> 6;

    // wave 0: reduce this batch's 64x10 partials + n; thread 0 adds g/bias
    if (w == 0) {
        const int base = ((b << 6) + lane) << 4;
        float trf = 0.f, tsf = 0.f;
        #pragma unroll
        for (int j = 0; j < 10; ++j) {
            trf += ws[base + j];
            tsf += ws[8192 + base + j];
        }
        float tr2 = trf * trf;
        float m0 = mask[(b << 8) + lane];
        float m1 = mask[(b << 8) + lane + 64];
        float m2 = mask[(b << 8) + lane + 128];
        float m3 = mask[(b << 8) + lane + 192];
        float nn = m0 * m0 + m1 * m1 + m2 * m2 + m3 * m3;
        #pragma unroll
        for (int off = 32; off > 0; off >>= 1) {
            trf += __shfl_down(trf, off);
            tr2 += __shfl_down(tr2, off);
            tsf += __shfl_down(tsf, off);
            nn  += __shfl_down(nn,  off);
        }
        if (lane == 0) {
            float n  = nn;
            float n2 = fmaxf(n - 1.f, 1.f);
            sstats[0] = trf / (64.f * n);
            sstats[1] = 1.f / sqrtf(tsf / (64.f * n2) - tr2 / (64.f * n * n2) + EPSF);
            sstats[2] = wt[f] * expf(wexp[f]) + wbias[f];
            sstats[3] = bias[f];
        }
    }
    __syncthreads();

    const float meanb = sstats[0];
    const float istd  = sstats[1];
    const float gs    = sstats[2];
    const float bs    = sstats[3];
    const float* __restrict__ xm = x + (size_t)mat * (NN * NN);
    float* __restrict__       om = out + (size_t)mat * (NN * NN);

    const int r0 = q << 6;
    const int j0 = lane << 2;               // 0..252: fixed per thread
    const float4 mj = *(const float4*)&md[j0];
    const float mjx = mj.x * istd * gs, mjy = mj.y * istd * gs,
                mjz = mj.z * istd * gs, mjw = mj.w * istd * gs;

    #pragma unroll
    for (int rr = 0; rr < 16; ++rr) {
        const int i = r0 + w + (rr << 2);   // wave-uniform row
        const float mi = md[i];             // LDS broadcast (wave-uniform)
        floatx4 o;
        if (mi != 0.f) {
            const float4 xv = *(const float4*)(xm + (size_t)i * NN + j0);
            o.x = (xv.x - (i == j0     ? meanb : 0.f)) * mjx * mi + (i == j0     ? bs : 0.f);
            o.y = (xv.y - (i == j0 + 1 ? meanb : 0.f)) * mjy * mi + (i == j0 + 1 ? bs : 0.f);
            o.z = (xv.z - (i == j0 + 2 ? meanb : 0.f)) * mjz * mi + (i == j0 + 2 ? bs : 0.f);
            o.w = (xv.w - (i == j0 + 3 ? meanb : 0.f)) * mjw * mi + (i == j0 + 3 ? bs : 0.f);
        } else {
            // masked-out row: x_norm row is identically zero; only bias diag survives
            o.x = (i == j0    ) ? bs : 0.f;
            o.y = (i == j0 + 1) ? bs : 0.f;
            o.z = (i == j0 + 2) ? bs : 0.f;
            o.w = (i == j0 + 3) ? bs : 0.f;
        }
        __builtin_nontemporal_store(o, (floatx4*)(om + (size_t)i * NN + j0));
    }
}

extern "C" void kernel_launch(void* const* d_in, const int* in_sizes, int n_in,
                              void* d_out, int out_size, void* d_ws, size_t ws_size,
                              hipStream_t stream) {
    const float* x     = (const float*)d_in[0];
    const float* mask  = (const float*)d_in[1];
    const float* wt    = (const float*)d_in[2];
    const float* wexp  = (const float*)d_in[3];
    const float* wbias = (const float*)d_in[4];
    const float* bias  = (const float*)d_in[5];
    float* out = (float*)d_out;
    float* ws  = (float*)d_ws;

    hipLaunchKernelGGL(k_traces, dim3(512, 10), dim3(256), 0, stream, x, mask, ws);
    hipLaunchKernelGGL(k_out,    dim3(512, 4),  dim3(256), 0, stream,
                       x, mask, wt, wexp, wbias, bias, ws, out);
}